// Round 12
// baseline (299.143 us; speedup 1.0000x reference)
//
#include <hip/hip_runtime.h>
#include <cstdint>
#include <cstddef>

#pragma clang fp contract(off)

constexpr int NIMG  = 16;
constexpr int NB0   = 19200;   // 80*80*3
constexpr int NB1   = 4800;    // 40*40*3
constexpr int NB2   = 1200;    // 20*20*3
constexpr int NBOX  = 25200;
constexpr int NCLS  = 80;
constexpr int NCH   = 85;
constexpr int NBINS = 4096;
constexpr int CAP   = 4096;
constexpr int NTOP  = 1000;
constexpr int NDET  = 100;
constexpr int WLCAP = 65536;   // worklist capacity
constexpr float IMGSZ = 640.0f;
constexpr float BIN_SCALE = 4096.0f / 0.75f;

constexpr int TILE    = 512;           // boxes per block
constexpr int TILES   = (NBOX + TILE - 1) / TILE;   // 50

constexpr int IOU_RPB = 40;            // rows per k_iou block (25 blocks/img)

// ---------------- XLA-CPU-matching transcendentals (verified absmax=0) ----------------
// Used ONLY for values that reach the output (emitted keys, box coords).
__device__ __forceinline__ float xla_expf(float x) {
  const float kLog2e = 1.44269504088896341f;
  const float kC1 = 0.693359375f;
  const float kC2 = -2.12194440e-4f;
  const float cp0 = 1.9875691500e-4f;
  const float cp1 = 1.3981999507e-3f;
  const float cp2 = 8.3334519073e-3f;
  const float cp3 = 4.1665795894e-2f;
  const float cp4 = 1.6666665459e-1f;
  const float cp5 = 5.0000001201e-1f;
  float xc = fminf(x, 88.3762626647950f);
  xc = fmaxf(xc, -88.3762626647949f);
  float fx = floorf(fmaf(xc, kLog2e, 0.5f));
  float xr = fmaf(fx, -kC1, xc);
  xr = fmaf(fx, -kC2, xr);
  float z = xr * xr;
  float y = fmaf(cp0, xr, cp1);
  y = fmaf(y, xr, cp2);
  y = fmaf(y, xr, cp3);
  y = fmaf(y, xr, cp4);
  y = fmaf(y, xr, cp5);
  y = fmaf(y, z, xr);
  y = y + 1.0f;
  int n = (int)fx;
  float two_n = __int_as_float((n + 127) << 23);
  float r = y * two_n;
  return fmaxf(r, xc);
}

__device__ __forceinline__ float ref_sigmoid(float x) {
  return 1.0f / (1.0f + xla_expf(-x));
}

// Fast monotone sigmoid for FILTERING only (err ~1e-7 << 1e-4 gate margins).
// Must be the IDENTICAL expression in k_passA and k_emit (bit-consistent).
__device__ __forceinline__ float fast_sigmoid(float x) {
  float e = __expf(-x);
  return __fdividef(1.0f, 1.0f + e);
}

__device__ __forceinline__ int score_bin(float s) {
  int b = (int)((s - 0.25f) * BIN_SCALE);
  return min(max(b, 0), NBINS - 1);
}

// ---------------- geometry helpers ----------------
__device__ __forceinline__ const float* locate(int img, int box,
    const float* __restrict__ p0, const float* __restrict__ p1, const float* __restrict__ p2,
    int& lvl, int& gx, int& gy, int& anc, float& stride) {
  const float* base; int r, W;
  if (box < NB0)            { lvl = 0; r = box;             W = 80; base = p0 + (size_t)img * NB0 * NCH; stride = 8.0f;  }
  else if (box < NB0 + NB1) { lvl = 1; r = box - NB0;       W = 40; base = p1 + (size_t)img * NB1 * NCH; stride = 16.0f; }
  else                      { lvl = 2; r = box - NB0 - NB1; W = 20; base = p2 + (size_t)img * NB2 * NCH; stride = 32.0f; }
  anc = r % 3;
  int cell = r / 3;
  gx = cell % W;
  gy = cell / W;
  return base + (size_t)r * NCH;
}

__device__ __forceinline__ float clip640(float v) {
  return fminf(fmaxf(v, 0.0f), IMGSZ);
}

// row pointer only (no grid coords)
__device__ __forceinline__ const float* row_ptr(int img, int box,
    const float* __restrict__ p0, const float* __restrict__ p1, const float* __restrict__ p2) {
  const float* base; int r;
  if (box < NB0)            { base = p0 + (size_t)img * NB0 * NCH; r = box; }
  else if (box < NB0 + NB1) { base = p1 + (size_t)img * NB1 * NCH; r = box - NB0; }
  else                      { base = p2 + (size_t)img * NB2 * NCH; r = box - NB0 - NB1; }
  return base + (size_t)r * NCH;
}

// ---------------- pass A: direct-from-global fast filter, histogram + per-box maxbin ----
// No LDS staging: each box row (340 B = 6 lines) is L1-resident across the 8
// threads x 11 strided reads that consume it. No per-chunk barriers; loads
// pipeline via TLP. LDS = 16 KB hist only -> higher occupancy.
// Fast conservative logit pre-filter skips ~70% of class sigmoids; the
// s > 0.2499 re-check keeps the histogram BIT-IDENTICAL to the unfiltered one.
__global__ __launch_bounds__(256) void k_passA(const float* __restrict__ p0,
    const float* __restrict__ p1, const float* __restrict__ p2,
    unsigned int* __restrict__ ghist, unsigned short* __restrict__ maxbin) {
  __shared__ unsigned int hist[NBINS];              // 16 KB
  const int tid = threadIdx.x;
  const int img  = blockIdx.x / TILES;
  const int tile = blockIdx.x % TILES;
  const int tbase = tile * TILE;
  const int nbox_tile = min(TILE, NBOX - tbase);

  for (int i = tid; i < NBINS; i += 256) hist[i] = 0u;
  __syncthreads();

  const int b_local = tid >> 3, part = tid & 7;
  for (int step = 0; step < TILE / 32; ++step) {
    int bl = step * 32 + b_local;
    int mb = 0;
    bool valid = (bl < nbox_tile);      // uniform within each 8-lane shfl group
    if (valid) {
      int box = tbase + bl;
      const float* row = row_ptr(img, box, p0, p1, p2);
      float obj = fast_sigmoid(row[4]);
      if (obj > 0.2499f) {
        float rr = 0.2499f / obj;
        float tcons = __logf(__fdividef(rr, 1.0f - rr)) - 0.05f;  // conservative
        #pragma unroll
        for (int cc = 0; cc < 10; ++cc) {
          float x = row[5 + part + 8 * cc];
          if (x > tcons) {
            float s = obj * fast_sigmoid(x);
            if (s > 0.2499f) {
              int bin = score_bin(s);
              atomicAdd(&hist[bin], 1u);
              mb = max(mb, bin + 1);    // stored = maxbin+1, 0 = none
            }
          }
        }
      }
    }
    mb = max(mb, __shfl_xor(mb, 1, 8));
    mb = max(mb, __shfl_xor(mb, 2, 8));
    mb = max(mb, __shfl_xor(mb, 4, 8));
    if (valid && part == 0)
      maxbin[(size_t)img * NBOX + tbase + bl] = (unsigned short)mb;
  }
  __syncthreads();

  for (int i = tid; i < NBINS; i += 256) {
    unsigned int v = hist[i];
    if (v) atomicAdd(&ghist[img * NBINS + i], v);
  }
}

// ---------------- per-image threshold bin with 2-bin safety slack ----------------
__global__ __launch_bounds__(256) void k_thresh(const unsigned int* __restrict__ ghist,
                                                int* __restrict__ tbin) {
  __shared__ unsigned int h[NBINS];
  __shared__ unsigned int psum[256];
  const int tid = threadIdx.x;
  const int img = blockIdx.x;

  for (int i = tid; i < NBINS; i += 256) h[i] = ghist[img * NBINS + i];
  __syncthreads();
  unsigned int ps = 0;
  for (int k = 0; k < 16; ++k) ps += h[tid * 16 + k];
  psum[tid] = ps;
  __syncthreads();
  if (tid == 0) {
    long long cum = 0;
    int tb = 0;
    bool found = false;
    for (int g = 255; g >= 0 && !found; --g) {
      if (cum + (long long)psum[g] >= NTOP) {
        for (int b = g * 16 + 15; b >= g * 16; --b) {
          cum += h[b];
          if (cum >= NTOP) { tb = b; found = true; break; }
        }
      } else {
        cum += psum[g];
      }
    }
    if (!found) tb = 0;
    int tc = (tb >= 2) ? tb - 2 : 0;
    for (int b = tb - 1; b >= tc; --b) cum += h[b];
    while (cum > CAP - 8 && tc < NBINS - 1) { cum -= h[tc]; ++tc; }  // pathological guard
    tbin[img] = tc;
  }
}

// ---------------- worklist: compact passing rows (dense, coalesced) ----------------
__global__ __launch_bounds__(256) void k_worklist(const unsigned short* __restrict__ maxbin,
    const int* __restrict__ tbin, unsigned int* __restrict__ worklist,
    int* __restrict__ wcnt) {
  __shared__ int lcnt;
  __shared__ int lbase;
  const int tid = threadIdx.x;
  if (tid == 0) lcnt = 0;
  __syncthreads();
  int idx = blockIdx.x * 256 + tid;
  bool pass = false;
  int my = 0;
  int img = 0, box = 0;
  if (idx < NIMG * NBOX) {
    img = idx / NBOX;
    box = idx - img * NBOX;
    int mb = (int)maxbin[idx];
    if (mb > tbin[img]) {            // mb-1 >= tc
      pass = true;
      my = atomicAdd(&lcnt, 1);
    }
  }
  __syncthreads();
  if (tid == 0 && lcnt > 0) lbase = atomicAdd(wcnt, lcnt);
  __syncthreads();
  if (pass) {
    int pos = lbase + my;
    if (pos < WLCAP) worklist[pos] = ((unsigned int)img << 16) | (unsigned int)box;
  }
}

// ---------------- emit: fast pre-screen, EXACT gates + values; wave-aggregated slots ----
__global__ __launch_bounds__(256) void k_emit(const float* __restrict__ p0,
    const float* __restrict__ p1, const float* __restrict__ p2,
    const unsigned int* __restrict__ worklist, const int* __restrict__ wcnt,
    const int* __restrict__ tbin, unsigned long long* __restrict__ cand,
    int* __restrict__ cnt) {
  int n = *wcnt;
  if (n > WLCAP) n = WLCAP;
  const int lane = threadIdx.x & 63;
  const int nthreads = gridDim.x * 256;
  for (int i0 = blockIdx.x * 256 + threadIdx.x; ; i0 += nthreads) {
    bool haverow = (i0 < n);
    if (__ballot(haverow) == 0ull) break;   // wave-uniform exit

    int img = 0, box = 0, nc = 0;
    const float* ptr = nullptr;
    float obj_e = -1.0f;
    unsigned int bm0 = 0, bm1 = 0, bm2 = 0;   // candidate bitmask (after exact gates)
    if (haverow) {
      unsigned int e = worklist[i0];
      img = (int)(e >> 16);
      box = (int)(e & 0xFFFFu);
      int lvl, gx, gy, anc; float stride;
      ptr = locate(img, box, p0, p1, p2, lvl, gx, gy, anc, stride);
      float obj_f = fast_sigmoid(ptr[4]);     // identical expression to k_passA
      if (obj_f > 0.2499f) {
        int tc = tbin[img];
        #pragma unroll 8
        for (int c = 0; c < NCLS; ++c) {
          float x = ptr[5 + c];
          float sf = obj_f * fast_sigmoid(x);
          if (sf > 0.2499f && score_bin(sf) >= tc) {
            if (obj_e < 0.0f) obj_e = ref_sigmoid(ptr[4]);   // lazy exact obj
            if (obj_e > 0.25f) {
              float se = obj_e * ref_sigmoid(x);             // exact gates
              if (se > 0.25f) {
                if (c < 32)      bm0 |= 1u << c;
                else if (c < 64) bm1 |= 1u << (c - 32);
                else             bm2 |= 1u << (c - 64);
                ++nc;
              }
            }
          }
        }
      }
    }

    // wave-aggregated base assignment, grouped by img
    int mybase = 0;
    unsigned long long active = __ballot(nc > 0);
    while (active) {
      int leader = __ffsll(active) - 1;
      int limg = __shfl(img, leader);
      bool mine = (nc > 0) && (img == limg);
      unsigned long long grp = __ballot(mine);
      int incl = mine ? nc : 0;
      #pragma unroll
      for (int d = 1; d < 64; d <<= 1) {
        int t = __shfl_up(incl, d);
        if (lane >= d) incl += t;
      }
      int hi = 63 - __clzll(grp);
      int total = __shfl(incl, hi);
      int base = 0;
      if (lane == leader) base = atomicAdd(&cnt[limg], total);
      base = __shfl(base, leader);
      if (mine) mybase = base + incl - nc;
      active &= ~grp;
    }

    // pass 2: emit exact keys for flagged classes
    if (nc > 0) {
      int pos = mybase;
      unsigned int ms[3] = { bm0, bm1, bm2 };
      #pragma unroll
      for (int w = 0; w < 3; ++w) {
        unsigned int m = ms[w];
        while (m) {
          int c = w * 32 + (__ffs(m) - 1);
          m &= m - 1;
          float se = obj_e * ref_sigmoid(ptr[5 + c]);   // exact value (bit-identical)
          if (pos < CAP) {
            unsigned int fi = (unsigned int)(box * NCLS + c);
            unsigned long long key =
                ((unsigned long long)__float_as_uint(se) << 32) |
                (unsigned long long)(0xFFFFFFFFu - fi);
            cand[(size_t)img * CAP + pos] = key;
          }
          ++pos;
        }
      }
    }
  }
}

// ---------------- sort + decode top-1000 into boxes8 (one block per image) ----------------
#define SIDX(i) ((i) + ((i) >> 4))

__global__ __launch_bounds__(256) void k_sort(const float* __restrict__ p0,
    const float* __restrict__ p1, const float* __restrict__ p2,
    const float* __restrict__ anchors, const unsigned long long* __restrict__ cand,
    const int* __restrict__ cnt_arr, float* __restrict__ boxes8) {
  __shared__ unsigned long long keys[CAP + CAP / 16];   // 34.8 KB (swizzled)
  __shared__ int n2_sh, cnt_sh;
  const int tid = threadIdx.x;
  const int img = blockIdx.x;

  if (tid == 0) {
    int c = cnt_arr[img];
    c = max(0, min(c, CAP));
    int n2 = 1024;
    while (n2 < c) n2 <<= 1;
    cnt_sh = c; n2_sh = n2;
  }
  __syncthreads();
  const int cnt = cnt_sh;
  const int n2  = n2_sh;

  const unsigned long long* c = cand + (size_t)img * CAP;
  for (int i = tid; i < n2; i += 256) keys[SIDX(i)] = (i < cnt) ? c[i] : 0ull;
  __syncthreads();

  for (int kk = 2; kk <= n2; kk <<= 1) {
    for (int j = kk >> 1; j > 0; j >>= 1) {
      for (int i = tid; i < n2; i += 256) {
        int l = i ^ j;
        if (l > i) {
          unsigned long long a = keys[SIDX(i)], b = keys[SIDX(l)];
          bool up = ((i & kk) == 0);
          bool sw = up ? (a < b) : (a > b);
          if (sw) { keys[SIDX(i)] = b; keys[SIDX(l)] = a; }
        }
      }
      __syncthreads();
    }
  }

  // decode top-1000 -> boxes8[img][1000][8] = {b0,b1,b2,b3,val,label,0,0}
  float* dst = boxes8 + (size_t)img * NTOP * 8;
  for (int i = tid; i < NTOP; i += 256) {
    unsigned long long key = keys[SIDX(i)];
    unsigned int v = (unsigned int)(key >> 32);
    float4 fa, fb;
    if (v) {
      unsigned int idx = 0xFFFFFFFFu - (unsigned int)(key & 0xFFFFFFFFu);
      int box = (int)(idx / NCLS);
      int l   = (int)(idx % NCLS);
      int lvl, gx, gy, anc; float stride;
      const float* ptr = locate(img, box, p0, p1, p2, lvl, gx, gy, anc, stride);
      float sx = ref_sigmoid(ptr[0]);
      float sy = ref_sigmoid(ptr[1]);
      float sw = ref_sigmoid(ptr[2]);
      float sh = ref_sigmoid(ptr[3]);
      float aw = anchors[(lvl * 3 + anc) * 2 + 0];
      float ah = anchors[(lvl * 3 + anc) * 2 + 1];
      float cx = (2.0f * sx - 0.5f + (float)gx) * stride;
      float cy = (2.0f * sy - 0.5f + (float)gy) * stride;
      float ww = (4.0f * (sw * sw)) * aw;
      float hh = (4.0f * (sh * sh)) * ah;
      fa.x = clip640(cx - ww * 0.5f);
      fa.y = clip640(cy - hh * 0.5f);
      fa.z = clip640(cx + ww * 0.5f);
      fa.w = clip640(cy + hh * 0.5f);
      fb.x = __uint_as_float(v);
      fb.y = (float)l;
      fb.z = 0.0f; fb.w = 0.0f;
    } else {
      fa.x = fa.y = fa.z = fa.w = 0.0f;
      fb.x = 0.0f; fb.y = -1.0f; fb.z = 0.0f; fb.w = 0.0f;
    }
    *(float4*)(dst + i * 8)     = fa;
    *(float4*)(dst + i * 8 + 4) = fb;
  }
}

// ---------------- IoU suppression matrix: bit[r][t] = iou(obx[r],obx[t]) > 0.45 ----------
__global__ __launch_bounds__(256) void k_iou(const float* __restrict__ boxes8,
                                             unsigned int* __restrict__ mat) {
  __shared__ float obx[NTOP * 5];   // stride 5 -> lane col-reads are 2-way (free)
  const int img = blockIdx.x / (NTOP / IOU_RPB);
  const int rg  = blockIdx.x % (NTOP / IOU_RPB);
  const float* src = boxes8 + (size_t)img * NTOP * 8;

  for (int t = threadIdx.x; t < NTOP; t += 256) {
    float4 fa = *(const float4*)(src + t * 8);
    float lab = src[t * 8 + 5];
    float off = lab * 4096.0f;          // exact fp32 (ref: lab*MAX_SIZE)
    obx[t * 5 + 0] = fa.x + off;
    obx[t * 5 + 1] = fa.y + off;
    obx[t * 5 + 2] = fa.z + off;
    obx[t * 5 + 3] = fa.w + off;
  }
  __syncthreads();

  const int wave = threadIdx.x >> 6;
  const int lane = threadIdx.x & 63;
  for (int task = wave; task < IOU_RPB * 16; task += 4) {
    int r = rg * IOU_RPB + (task >> 4);
    int w = task & 15;
    float a0 = obx[r * 5 + 0], a1 = obx[r * 5 + 1];   // broadcast reads
    float a2 = obx[r * 5 + 2], a3 = obx[r * 5 + 3];
    float areaA = (a2 - a0) * (a3 - a1);
    int col = w * 64 + lane;
    bool bit = false;
    if (col < NTOP) {
      float o0 = obx[col * 5 + 0], o1 = obx[col * 5 + 1];
      float o2 = obx[col * 5 + 2], o3 = obx[col * 5 + 3];
      float ltx = fmaxf(a0, o0);
      float lty = fmaxf(a1, o1);
      float rbx = fminf(a2, o2);
      float rby = fminf(a3, o3);
      float wx = fmaxf(rbx - ltx, 0.0f);
      float wy = fmaxf(rby - lty, 0.0f);
      float inter = wx * wy;
      float a2r = (o2 - o0) * (o3 - o1);
      float denom = areaA + a2r - inter + 1e-7f;      // ((a1+a2)-inter)+1e-7, contract off
      bit = (inter / denom) > 0.45f;
    }
    unsigned long long m = __ballot(bit);
    if (lane == 0)
      *(unsigned long long*)(mat + ((size_t)img * NTOP + r) * 32 + w * 2) = m;
  }
}

// ---------------- NMS greedy: O(1) serial work per pick ----------
__global__ __launch_bounds__(64) void k_nms(const unsigned int* __restrict__ mat,
    const float* __restrict__ boxes8, const float* __restrict__ scalef,
    float* __restrict__ out) {
  __shared__ uint4 mat_lds4[NTOP * 8];   // 1000 rows x 32 u32 = 128000 B
  unsigned int* mat_lds = (unsigned int*)mat_lds4;
  const int lane = threadIdx.x;
  const int img = blockIdx.x;
  const float* src = boxes8 + (size_t)img * NTOP * 8;

  const uint4* msrc = (const uint4*)(mat + (size_t)img * NTOP * 32);
  for (int i = lane; i < NTOP * 8; i += 64) mat_lds4[i] = msrc[i];

  // alive init: lane l (<32) owns u32 word for bits t in [32l, 32l+32)
  unsigned int aw = 0u;
  for (int w = 0; w < 16; ++w) {
    int t = w * 64 + lane;
    float va = (t < NTOP) ? src[t * 8 + 4] : 0.0f;
    unsigned long long b = __ballot(va > 0.0f);
    if (lane == 2 * w)     aw = (unsigned int)b;
    if (lane == 2 * w + 1) aw = (unsigned int)(b >> 32);
  }
  if (lane >= 32) aw = 0u;
  __syncthreads();

  int pj0 = -1, pj1 = -1;
  for (int i = 0; i < NDET; ++i) {
    unsigned long long bal = __ballot(aw != 0u);
    int j = -1;
    if (bal != 0ull) {
      int L = __ffsll(bal) - 1;
      unsigned int wL = (unsigned int)__shfl((int)aw, L);
      j = L * 32 + (__ffs(wL) - 1);
    }
    if (lane == (i & 63)) { if (i < 64) pj0 = j; else pj1 = j; }
    if (j >= 0 && lane < 32) aw &= ~mat_lds[j * 32 + lane];   // conflict-free
  }

  // parallel emit
  const float scf = scalef[img];
  #pragma unroll
  for (int rep = 0; rep < 2; ++rep) {
    int i = rep * 64 + lane;
    if (i >= NDET) break;
    int j = (rep == 0) ? pj0 : pj1;
    float* orow = out + ((size_t)img * NDET + i) * 6;
    if (j < 0) {
      orow[0] = 0.0f; orow[1] = 0.0f; orow[2] = 0.0f;
      orow[3] = 0.0f; orow[4] = 0.0f; orow[5] = -1.0f;
    } else {
      float4 fa = *(const float4*)(src + j * 8);
      float va = src[j * 8 + 4];
      float lb = src[j * 8 + 5];
      orow[0] = fa.x / scf; orow[1] = fa.y / scf;
      orow[2] = fa.z / scf; orow[3] = fa.w / scf;
      orow[4] = va;
      orow[5] = lb;
    }
  }
}

// ---------------- launcher ----------------
extern "C" void kernel_launch(void* const* d_in, const int* in_sizes, int n_in,
                              void* d_out, int out_size, void* d_ws, size_t ws_size,
                              hipStream_t stream) {
  const float* p0 = (const float*)d_in[0];
  const float* p1 = (const float*)d_in[1];
  const float* p2 = (const float*)d_in[2];
  const float* anchors = (const float*)d_in[3];
  const float* scalef  = (const float*)d_in[4];
  float* out = (float*)d_out;

  char* w = (char*)d_ws;
  // layout (bytes): ghist 262144 | cnt 64 | tbin 64 | wcnt 64 | cand 524288 |
  //   maxbin 806400 | worklist 262144 | boxes8 512000 | mat 2048000  (~4.42 MB)
  unsigned int* ghist = (unsigned int*)(w);
  int* cnt  = (int*)(w + 262144);
  int* tbin = (int*)(w + 262208);
  int* wcnt = (int*)(w + 262272);
  unsigned long long* cand = (unsigned long long*)(w + 262336);
  unsigned short* maxbin = (unsigned short*)(w + 262336 + 524288);       // 786624
  unsigned int* worklist = (unsigned int*)(w + 786624 + 806400);         // 1593024
  float* boxes8 = (float*)(w + 1593024 + 262144);                        // 1855168
  unsigned int* mat = (unsigned int*)(w + 1855168 + 512000);             // 2367168

  hipMemsetAsync(ghist, 0, 262144 + 192, stream);   // hist + cnt + tbin + wcnt

  k_passA<<<dim3(NIMG * TILES), dim3(256), 0, stream>>>(p0, p1, p2, ghist, maxbin);
  k_thresh<<<dim3(NIMG), dim3(256), 0, stream>>>(ghist, tbin);
  k_worklist<<<dim3((NIMG * NBOX + 255) / 256), dim3(256), 0, stream>>>(maxbin, tbin, worklist, wcnt);
  k_emit<<<dim3(256), dim3(256), 0, stream>>>(p0, p1, p2, worklist, wcnt, tbin, cand, cnt);
  k_sort<<<dim3(NIMG), dim3(256), 0, stream>>>(p0, p1, p2, anchors, cand, cnt, boxes8);
  k_iou<<<dim3(NIMG * (NTOP / IOU_RPB)), dim3(256), 0, stream>>>(boxes8, mat);
  k_nms<<<dim3(NIMG), dim3(64), 0, stream>>>(mat, boxes8, scalef, out);
}

// Round 13
// 286.429 us; speedup vs baseline: 1.0444x; 1.0444x over previous
//
#include <hip/hip_runtime.h>
#include <cstdint>
#include <cstddef>

#pragma clang fp contract(off)

constexpr int NIMG  = 16;
constexpr int NB0   = 19200;   // 80*80*3
constexpr int NB1   = 4800;    // 40*40*3
constexpr int NB2   = 1200;    // 20*20*3
constexpr int NBOX  = 25200;
constexpr int NCLS  = 80;
constexpr int NCH   = 85;
constexpr int NBINS = 4096;
constexpr int CAP   = 4096;
constexpr int NTOP  = 1000;
constexpr int NDET  = 100;
constexpr int WLCAP = 65536;   // worklist capacity
constexpr float IMGSZ = 640.0f;
constexpr float BIN_SCALE = 4096.0f / 0.75f;

// passA tiling: TILE=128 -> 16*197 = 3152 blocks (~12.3/CU submitted, 8/CU
// resident = full 32 waves/CU). Round-12 post-mortem: TILE=512 gave an
// 800-block grid = 3.1 blocks/CU = 39% occupancy ceiling — grid-limited for
// three rounds straight, invariant under all within-block optimizations.
constexpr int TILE    = 128;
constexpr int TILES   = (NBOX + TILE - 1) / TILE;   // 197

constexpr int IOU_RPB = 40;            // rows per k_iou block (25 blocks/img)

// ---------------- XLA-CPU-matching transcendentals (verified absmax=0) ----------------
// Used ONLY for values that reach the output (emitted keys, box coords).
__device__ __forceinline__ float xla_expf(float x) {
  const float kLog2e = 1.44269504088896341f;
  const float kC1 = 0.693359375f;
  const float kC2 = -2.12194440e-4f;
  const float cp0 = 1.9875691500e-4f;
  const float cp1 = 1.3981999507e-3f;
  const float cp2 = 8.3334519073e-3f;
  const float cp3 = 4.1665795894e-2f;
  const float cp4 = 1.6666665459e-1f;
  const float cp5 = 5.0000001201e-1f;
  float xc = fminf(x, 88.3762626647950f);
  xc = fmaxf(xc, -88.3762626647949f);
  float fx = floorf(fmaf(xc, kLog2e, 0.5f));
  float xr = fmaf(fx, -kC1, xc);
  xr = fmaf(fx, -kC2, xr);
  float z = xr * xr;
  float y = fmaf(cp0, xr, cp1);
  y = fmaf(y, xr, cp2);
  y = fmaf(y, xr, cp3);
  y = fmaf(y, xr, cp4);
  y = fmaf(y, xr, cp5);
  y = fmaf(y, z, xr);
  y = y + 1.0f;
  int n = (int)fx;
  float two_n = __int_as_float((n + 127) << 23);
  float r = y * two_n;
  return fmaxf(r, xc);
}

__device__ __forceinline__ float ref_sigmoid(float x) {
  return 1.0f / (1.0f + xla_expf(-x));
}

// Fast monotone sigmoid for FILTERING only (err ~1e-7 << 1e-4 gate margins).
// Must be the IDENTICAL expression in k_passA and k_emit (bit-consistent).
__device__ __forceinline__ float fast_sigmoid(float x) {
  float e = __expf(-x);
  return __fdividef(1.0f, 1.0f + e);
}

__device__ __forceinline__ int score_bin(float s) {
  int b = (int)((s - 0.25f) * BIN_SCALE);
  return min(max(b, 0), NBINS - 1);
}

// ---------------- geometry helpers ----------------
__device__ __forceinline__ const float* locate(int img, int box,
    const float* __restrict__ p0, const float* __restrict__ p1, const float* __restrict__ p2,
    int& lvl, int& gx, int& gy, int& anc, float& stride) {
  const float* base; int r, W;
  if (box < NB0)            { lvl = 0; r = box;             W = 80; base = p0 + (size_t)img * NB0 * NCH; stride = 8.0f;  }
  else if (box < NB0 + NB1) { lvl = 1; r = box - NB0;       W = 40; base = p1 + (size_t)img * NB1 * NCH; stride = 16.0f; }
  else                      { lvl = 2; r = box - NB0 - NB1; W = 20; base = p2 + (size_t)img * NB2 * NCH; stride = 32.0f; }
  anc = r % 3;
  int cell = r / 3;
  gx = cell % W;
  gy = cell / W;
  return base + (size_t)r * NCH;
}

__device__ __forceinline__ float clip640(float v) {
  return fminf(fmaxf(v, 0.0f), IMGSZ);
}

// row pointer only (no grid coords)
__device__ __forceinline__ const float* row_ptr(int img, int box,
    const float* __restrict__ p0, const float* __restrict__ p1, const float* __restrict__ p2) {
  const float* base; int r;
  if (box < NB0)            { base = p0 + (size_t)img * NB0 * NCH; r = box; }
  else if (box < NB0 + NB1) { base = p1 + (size_t)img * NB1 * NCH; r = box - NB0; }
  else                      { base = p2 + (size_t)img * NB2 * NCH; r = box - NB0 - NB1; }
  return base + (size_t)r * NCH;
}

// ---------------- pass A: direct-from-global fast filter, histogram + per-box maxbin ----
__global__ __launch_bounds__(256) void k_passA(const float* __restrict__ p0,
    const float* __restrict__ p1, const float* __restrict__ p2,
    unsigned int* __restrict__ ghist, unsigned short* __restrict__ maxbin) {
  __shared__ unsigned int hist[NBINS];              // 16 KB
  const int tid = threadIdx.x;
  const int img  = blockIdx.x / TILES;
  const int tile = blockIdx.x % TILES;
  const int tbase = tile * TILE;
  const int nbox_tile = min(TILE, NBOX - tbase);

  for (int i = tid; i < NBINS; i += 256) hist[i] = 0u;
  __syncthreads();

  const int b_local = tid >> 3, part = tid & 7;
  #pragma unroll
  for (int step = 0; step < TILE / 32; ++step) {
    int bl = step * 32 + b_local;
    int mb = 0;
    bool valid = (bl < nbox_tile);      // uniform within each 8-lane shfl group
    if (valid) {
      int box = tbase + bl;
      const float* row = row_ptr(img, box, p0, p1, p2);
      float obj = fast_sigmoid(row[4]);
      if (obj > 0.2499f) {
        float rr = 0.2499f / obj;
        float tcons = __logf(__fdividef(rr, 1.0f - rr)) - 0.05f;  // conservative
        #pragma unroll
        for (int cc = 0; cc < 10; ++cc) {
          float x = row[5 + part + 8 * cc];
          if (x > tcons) {
            float s = obj * fast_sigmoid(x);
            if (s > 0.2499f) {
              int bin = score_bin(s);
              atomicAdd(&hist[bin], 1u);
              mb = max(mb, bin + 1);    // stored = maxbin+1, 0 = none
            }
          }
        }
      }
    }
    mb = max(mb, __shfl_xor(mb, 1, 8));
    mb = max(mb, __shfl_xor(mb, 2, 8));
    mb = max(mb, __shfl_xor(mb, 4, 8));
    if (valid && part == 0)
      maxbin[(size_t)img * NBOX + tbase + bl] = (unsigned short)mb;
  }
  __syncthreads();

  for (int i = tid; i < NBINS; i += 256) {
    unsigned int v = hist[i];
    if (v) atomicAdd(&ghist[img * NBINS + i], v);   // only ~50-100 nonzero bins/block
  }
}

// ---------------- per-image threshold bin with 2-bin safety slack ----------------
__global__ __launch_bounds__(256) void k_thresh(const unsigned int* __restrict__ ghist,
                                                int* __restrict__ tbin) {
  __shared__ unsigned int h[NBINS];
  __shared__ unsigned int psum[256];
  const int tid = threadIdx.x;
  const int img = blockIdx.x;

  for (int i = tid; i < NBINS; i += 256) h[i] = ghist[img * NBINS + i];
  __syncthreads();
  unsigned int ps = 0;
  for (int k = 0; k < 16; ++k) ps += h[tid * 16 + k];
  psum[tid] = ps;
  __syncthreads();
  if (tid == 0) {
    long long cum = 0;
    int tb = 0;
    bool found = false;
    for (int g = 255; g >= 0 && !found; --g) {
      if (cum + (long long)psum[g] >= NTOP) {
        for (int b = g * 16 + 15; b >= g * 16; --b) {
          cum += h[b];
          if (cum >= NTOP) { tb = b; found = true; break; }
        }
      } else {
        cum += psum[g];
      }
    }
    if (!found) tb = 0;
    int tc = (tb >= 2) ? tb - 2 : 0;
    for (int b = tb - 1; b >= tc; --b) cum += h[b];
    while (cum > CAP - 8 && tc < NBINS - 1) { cum -= h[tc]; ++tc; }  // pathological guard
    tbin[img] = tc;
  }
}

// ---------------- worklist: compact passing rows (dense, coalesced) ----------------
__global__ __launch_bounds__(256) void k_worklist(const unsigned short* __restrict__ maxbin,
    const int* __restrict__ tbin, unsigned int* __restrict__ worklist,
    int* __restrict__ wcnt) {
  __shared__ int lcnt;
  __shared__ int lbase;
  const int tid = threadIdx.x;
  if (tid == 0) lcnt = 0;
  __syncthreads();
  int idx = blockIdx.x * 256 + tid;
  bool pass = false;
  int my = 0;
  int img = 0, box = 0;
  if (idx < NIMG * NBOX) {
    img = idx / NBOX;
    box = idx - img * NBOX;
    int mb = (int)maxbin[idx];
    if (mb > tbin[img]) {            // mb-1 >= tc
      pass = true;
      my = atomicAdd(&lcnt, 1);
    }
  }
  __syncthreads();
  if (tid == 0 && lcnt > 0) lbase = atomicAdd(wcnt, lcnt);
  __syncthreads();
  if (pass) {
    int pos = lbase + my;
    if (pos < WLCAP) worklist[pos] = ((unsigned int)img << 16) | (unsigned int)box;
  }
}

// ---------------- emit: fast pre-screen, EXACT gates + values; wave-aggregated slots ----
__global__ __launch_bounds__(256) void k_emit(const float* __restrict__ p0,
    const float* __restrict__ p1, const float* __restrict__ p2,
    const unsigned int* __restrict__ worklist, const int* __restrict__ wcnt,
    const int* __restrict__ tbin, unsigned long long* __restrict__ cand,
    int* __restrict__ cnt) {
  int n = *wcnt;
  if (n > WLCAP) n = WLCAP;
  const int lane = threadIdx.x & 63;
  const int nthreads = gridDim.x * 256;
  for (int i0 = blockIdx.x * 256 + threadIdx.x; ; i0 += nthreads) {
    bool haverow = (i0 < n);
    if (__ballot(haverow) == 0ull) break;   // wave-uniform exit

    int img = 0, box = 0, nc = 0;
    const float* ptr = nullptr;
    float obj_e = -1.0f;
    unsigned int bm0 = 0, bm1 = 0, bm2 = 0;   // candidate bitmask (after exact gates)
    if (haverow) {
      unsigned int e = worklist[i0];
      img = (int)(e >> 16);
      box = (int)(e & 0xFFFFu);
      int lvl, gx, gy, anc; float stride;
      ptr = locate(img, box, p0, p1, p2, lvl, gx, gy, anc, stride);
      float obj_f = fast_sigmoid(ptr[4]);     // identical expression to k_passA
      if (obj_f > 0.2499f) {
        int tc = tbin[img];
        #pragma unroll 8
        for (int c = 0; c < NCLS; ++c) {
          float x = ptr[5 + c];
          float sf = obj_f * fast_sigmoid(x);
          if (sf > 0.2499f && score_bin(sf) >= tc) {
            if (obj_e < 0.0f) obj_e = ref_sigmoid(ptr[4]);   // lazy exact obj
            if (obj_e > 0.25f) {
              float se = obj_e * ref_sigmoid(x);             // exact gates
              if (se > 0.25f) {
                if (c < 32)      bm0 |= 1u << c;
                else if (c < 64) bm1 |= 1u << (c - 32);
                else             bm2 |= 1u << (c - 64);
                ++nc;
              }
            }
          }
        }
      }
    }

    // wave-aggregated base assignment, grouped by img
    int mybase = 0;
    unsigned long long active = __ballot(nc > 0);
    while (active) {
      int leader = __ffsll(active) - 1;
      int limg = __shfl(img, leader);
      bool mine = (nc > 0) && (img == limg);
      unsigned long long grp = __ballot(mine);
      int incl = mine ? nc : 0;
      #pragma unroll
      for (int d = 1; d < 64; d <<= 1) {
        int t = __shfl_up(incl, d);
        if (lane >= d) incl += t;
      }
      int hi = 63 - __clzll(grp);
      int total = __shfl(incl, hi);
      int base = 0;
      if (lane == leader) base = atomicAdd(&cnt[limg], total);
      base = __shfl(base, leader);
      if (mine) mybase = base + incl - nc;
      active &= ~grp;
    }

    // pass 2: emit exact keys for flagged classes
    if (nc > 0) {
      int pos = mybase;
      unsigned int ms[3] = { bm0, bm1, bm2 };
      #pragma unroll
      for (int w = 0; w < 3; ++w) {
        unsigned int m = ms[w];
        while (m) {
          int c = w * 32 + (__ffs(m) - 1);
          m &= m - 1;
          float se = obj_e * ref_sigmoid(ptr[5 + c]);   // exact value (bit-identical)
          if (pos < CAP) {
            unsigned int fi = (unsigned int)(box * NCLS + c);
            unsigned long long key =
                ((unsigned long long)__float_as_uint(se) << 32) |
                (unsigned long long)(0xFFFFFFFFu - fi);
            cand[(size_t)img * CAP + pos] = key;
          }
          ++pos;
        }
      }
    }
  }
}

// ---------------- sort + decode top-1000 into boxes8 (one block per image) ----------------
#define SIDX(i) ((i) + ((i) >> 4))

__global__ __launch_bounds__(256) void k_sort(const float* __restrict__ p0,
    const float* __restrict__ p1, const float* __restrict__ p2,
    const float* __restrict__ anchors, const unsigned long long* __restrict__ cand,
    const int* __restrict__ cnt_arr, float* __restrict__ boxes8) {
  __shared__ unsigned long long keys[CAP + CAP / 16];   // 34.8 KB (swizzled)
  __shared__ int n2_sh, cnt_sh;
  const int tid = threadIdx.x;
  const int img = blockIdx.x;

  if (tid == 0) {
    int c = cnt_arr[img];
    c = max(0, min(c, CAP));
    int n2 = 1024;
    while (n2 < c) n2 <<= 1;
    cnt_sh = c; n2_sh = n2;
  }
  __syncthreads();
  const int cnt = cnt_sh;
  const int n2  = n2_sh;

  const unsigned long long* c = cand + (size_t)img * CAP;
  for (int i = tid; i < n2; i += 256) keys[SIDX(i)] = (i < cnt) ? c[i] : 0ull;
  __syncthreads();

  for (int kk = 2; kk <= n2; kk <<= 1) {
    for (int j = kk >> 1; j > 0; j >>= 1) {
      for (int i = tid; i < n2; i += 256) {
        int l = i ^ j;
        if (l > i) {
          unsigned long long a = keys[SIDX(i)], b = keys[SIDX(l)];
          bool up = ((i & kk) == 0);
          bool sw = up ? (a < b) : (a > b);
          if (sw) { keys[SIDX(i)] = b; keys[SIDX(l)] = a; }
        }
      }
      __syncthreads();
    }
  }

  // decode top-1000 -> boxes8[img][1000][8] = {b0,b1,b2,b3,val,label,0,0}
  float* dst = boxes8 + (size_t)img * NTOP * 8;
  for (int i = tid; i < NTOP; i += 256) {
    unsigned long long key = keys[SIDX(i)];
    unsigned int v = (unsigned int)(key >> 32);
    float4 fa, fb;
    if (v) {
      unsigned int idx = 0xFFFFFFFFu - (unsigned int)(key & 0xFFFFFFFFu);
      int box = (int)(idx / NCLS);
      int l   = (int)(idx % NCLS);
      int lvl, gx, gy, anc; float stride;
      const float* ptr = locate(img, box, p0, p1, p2, lvl, gx, gy, anc, stride);
      float sx = ref_sigmoid(ptr[0]);
      float sy = ref_sigmoid(ptr[1]);
      float sw = ref_sigmoid(ptr[2]);
      float sh = ref_sigmoid(ptr[3]);
      float aw = anchors[(lvl * 3 + anc) * 2 + 0];
      float ah = anchors[(lvl * 3 + anc) * 2 + 1];
      float cx = (2.0f * sx - 0.5f + (float)gx) * stride;
      float cy = (2.0f * sy - 0.5f + (float)gy) * stride;
      float ww = (4.0f * (sw * sw)) * aw;
      float hh = (4.0f * (sh * sh)) * ah;
      fa.x = clip640(cx - ww * 0.5f);
      fa.y = clip640(cy - hh * 0.5f);
      fa.z = clip640(cx + ww * 0.5f);
      fa.w = clip640(cy + hh * 0.5f);
      fb.x = __uint_as_float(v);
      fb.y = (float)l;
      fb.z = 0.0f; fb.w = 0.0f;
    } else {
      fa.x = fa.y = fa.z = fa.w = 0.0f;
      fb.x = 0.0f; fb.y = -1.0f; fb.z = 0.0f; fb.w = 0.0f;
    }
    *(float4*)(dst + i * 8)     = fa;
    *(float4*)(dst + i * 8 + 4) = fb;
  }
}

// ---------------- IoU suppression matrix: bit[r][t] = iou(obx[r],obx[t]) > 0.45 ----------
__global__ __launch_bounds__(256) void k_iou(const float* __restrict__ boxes8,
                                             unsigned int* __restrict__ mat) {
  __shared__ float obx[NTOP * 5];   // stride 5 -> lane col-reads are 2-way (free)
  const int img = blockIdx.x / (NTOP / IOU_RPB);
  const int rg  = blockIdx.x % (NTOP / IOU_RPB);
  const float* src = boxes8 + (size_t)img * NTOP * 8;

  for (int t = threadIdx.x; t < NTOP; t += 256) {
    float4 fa = *(const float4*)(src + t * 8);
    float lab = src[t * 8 + 5];
    float off = lab * 4096.0f;          // exact fp32 (ref: lab*MAX_SIZE)
    obx[t * 5 + 0] = fa.x + off;
    obx[t * 5 + 1] = fa.y + off;
    obx[t * 5 + 2] = fa.z + off;
    obx[t * 5 + 3] = fa.w + off;
  }
  __syncthreads();

  const int wave = threadIdx.x >> 6;
  const int lane = threadIdx.x & 63;
  for (int task = wave; task < IOU_RPB * 16; task += 4) {
    int r = rg * IOU_RPB + (task >> 4);
    int w = task & 15;
    float a0 = obx[r * 5 + 0], a1 = obx[r * 5 + 1];   // broadcast reads
    float a2 = obx[r * 5 + 2], a3 = obx[r * 5 + 3];
    float areaA = (a2 - a0) * (a3 - a1);
    int col = w * 64 + lane;
    bool bit = false;
    if (col < NTOP) {
      float o0 = obx[col * 5 + 0], o1 = obx[col * 5 + 1];
      float o2 = obx[col * 5 + 2], o3 = obx[col * 5 + 3];
      float ltx = fmaxf(a0, o0);
      float lty = fmaxf(a1, o1);
      float rbx = fminf(a2, o2);
      float rby = fminf(a3, o3);
      float wx = fmaxf(rbx - ltx, 0.0f);
      float wy = fmaxf(rby - lty, 0.0f);
      float inter = wx * wy;
      float a2r = (o2 - o0) * (o3 - o1);
      float denom = areaA + a2r - inter + 1e-7f;      // ((a1+a2)-inter)+1e-7, contract off
      bit = (inter / denom) > 0.45f;
    }
    unsigned long long m = __ballot(bit);
    if (lane == 0)
      *(unsigned long long*)(mat + ((size_t)img * NTOP + r) * 32 + w * 2) = m;
  }
}

// ---------------- NMS greedy: O(1) serial work per pick ----------
__global__ __launch_bounds__(64) void k_nms(const unsigned int* __restrict__ mat,
    const float* __restrict__ boxes8, const float* __restrict__ scalef,
    float* __restrict__ out) {
  __shared__ uint4 mat_lds4[NTOP * 8];   // 1000 rows x 32 u32 = 128000 B
  unsigned int* mat_lds = (unsigned int*)mat_lds4;
  const int lane = threadIdx.x;
  const int img = blockIdx.x;
  const float* src = boxes8 + (size_t)img * NTOP * 8;

  const uint4* msrc = (const uint4*)(mat + (size_t)img * NTOP * 32);
  for (int i = lane; i < NTOP * 8; i += 64) mat_lds4[i] = msrc[i];

  // alive init: lane l (<32) owns u32 word for bits t in [32l, 32l+32)
  unsigned int aw = 0u;
  for (int w = 0; w < 16; ++w) {
    int t = w * 64 + lane;
    float va = (t < NTOP) ? src[t * 8 + 4] : 0.0f;
    unsigned long long b = __ballot(va > 0.0f);
    if (lane == 2 * w)     aw = (unsigned int)b;
    if (lane == 2 * w + 1) aw = (unsigned int)(b >> 32);
  }
  if (lane >= 32) aw = 0u;
  __syncthreads();

  int pj0 = -1, pj1 = -1;
  for (int i = 0; i < NDET; ++i) {
    unsigned long long bal = __ballot(aw != 0u);
    int j = -1;
    if (bal != 0ull) {
      int L = __ffsll(bal) - 1;
      unsigned int wL = (unsigned int)__shfl((int)aw, L);
      j = L * 32 + (__ffs(wL) - 1);
    }
    if (lane == (i & 63)) { if (i < 64) pj0 = j; else pj1 = j; }
    if (j >= 0 && lane < 32) aw &= ~mat_lds[j * 32 + lane];   // conflict-free
  }

  // parallel emit
  const float scf = scalef[img];
  #pragma unroll
  for (int rep = 0; rep < 2; ++rep) {
    int i = rep * 64 + lane;
    if (i >= NDET) break;
    int j = (rep == 0) ? pj0 : pj1;
    float* orow = out + ((size_t)img * NDET + i) * 6;
    if (j < 0) {
      orow[0] = 0.0f; orow[1] = 0.0f; orow[2] = 0.0f;
      orow[3] = 0.0f; orow[4] = 0.0f; orow[5] = -1.0f;
    } else {
      float4 fa = *(const float4*)(src + j * 8);
      float va = src[j * 8 + 4];
      float lb = src[j * 8 + 5];
      orow[0] = fa.x / scf; orow[1] = fa.y / scf;
      orow[2] = fa.z / scf; orow[3] = fa.w / scf;
      orow[4] = va;
      orow[5] = lb;
    }
  }
}

// ---------------- launcher ----------------
extern "C" void kernel_launch(void* const* d_in, const int* in_sizes, int n_in,
                              void* d_out, int out_size, void* d_ws, size_t ws_size,
                              hipStream_t stream) {
  const float* p0 = (const float*)d_in[0];
  const float* p1 = (const float*)d_in[1];
  const float* p2 = (const float*)d_in[2];
  const float* anchors = (const float*)d_in[3];
  const float* scalef  = (const float*)d_in[4];
  float* out = (float*)d_out;

  char* w = (char*)d_ws;
  // layout (bytes): ghist 262144 | cnt 64 | tbin 64 | wcnt 64 | cand 524288 |
  //   maxbin 806400 | worklist 262144 | boxes8 512000 | mat 2048000  (~4.42 MB)
  unsigned int* ghist = (unsigned int*)(w);
  int* cnt  = (int*)(w + 262144);
  int* tbin = (int*)(w + 262208);
  int* wcnt = (int*)(w + 262272);
  unsigned long long* cand = (unsigned long long*)(w + 262336);
  unsigned short* maxbin = (unsigned short*)(w + 262336 + 524288);       // 786624
  unsigned int* worklist = (unsigned int*)(w + 786624 + 806400);         // 1593024
  float* boxes8 = (float*)(w + 1593024 + 262144);                        // 1855168
  unsigned int* mat = (unsigned int*)(w + 1855168 + 512000);             // 2367168

  hipMemsetAsync(ghist, 0, 262144 + 192, stream);   // hist + cnt + tbin + wcnt

  k_passA<<<dim3(NIMG * TILES), dim3(256), 0, stream>>>(p0, p1, p2, ghist, maxbin);
  k_thresh<<<dim3(NIMG), dim3(256), 0, stream>>>(ghist, tbin);
  k_worklist<<<dim3((NIMG * NBOX + 255) / 256), dim3(256), 0, stream>>>(maxbin, tbin, worklist, wcnt);
  k_emit<<<dim3(256), dim3(256), 0, stream>>>(p0, p1, p2, worklist, wcnt, tbin, cand, cnt);
  k_sort<<<dim3(NIMG), dim3(256), 0, stream>>>(p0, p1, p2, anchors, cand, cnt, boxes8);
  k_iou<<<dim3(NIMG * (NTOP / IOU_RPB)), dim3(256), 0, stream>>>(boxes8, mat);
  k_nms<<<dim3(NIMG), dim3(64), 0, stream>>>(mat, boxes8, scalef, out);
}

// Round 14
// 224.257 us; speedup vs baseline: 1.3339x; 1.2772x over previous
//
#include <hip/hip_runtime.h>
#include <cstdint>
#include <cstddef>

#pragma clang fp contract(off)

constexpr int NIMG  = 16;
constexpr int NB0   = 19200;   // 80*80*3
constexpr int NB1   = 4800;    // 40*40*3
constexpr int NB2   = 1200;    // 20*20*3
constexpr int NBOX  = 25200;
constexpr int NCLS  = 80;
constexpr int NCH   = 85;
constexpr int NBINS = 4096;
constexpr int CAP   = 4096;
constexpr int NTOP  = 1000;
constexpr int NDET  = 100;
constexpr float IMGSZ = 640.0f;
constexpr float BIN_SCALE = 4096.0f / 0.75f;

constexpr int TILE    = 128;
constexpr int TILES   = (NBOX + TILE - 1) / TILE;   // 197

constexpr int IOU_RPB = 40;            // rows per k_iou block (25 blocks/img)
constexpr int LOWBIN  = 546;           // s < 0.35: lump-counted (tb ~ 3000 >> 548)

// 4-byte-aligned vector types: gfx9 global_load_dwordx4 needs only dword align
typedef float float4a __attribute__((ext_vector_type(4), aligned(4)));
typedef float float2a __attribute__((ext_vector_type(2), aligned(4)));

// ---------------- XLA-CPU-matching transcendentals (verified absmax=0) ----------------
__device__ __forceinline__ float xla_expf(float x) {
  const float kLog2e = 1.44269504088896341f;
  const float kC1 = 0.693359375f;
  const float kC2 = -2.12194440e-4f;
  const float cp0 = 1.9875691500e-4f;
  const float cp1 = 1.3981999507e-3f;
  const float cp2 = 8.3334519073e-3f;
  const float cp3 = 4.1665795894e-2f;
  const float cp4 = 1.6666665459e-1f;
  const float cp5 = 5.0000001201e-1f;
  float xc = fminf(x, 88.3762626647950f);
  xc = fmaxf(xc, -88.3762626647949f);
  float fx = floorf(fmaf(xc, kLog2e, 0.5f));
  float xr = fmaf(fx, -kC1, xc);
  xr = fmaf(fx, -kC2, xr);
  float z = xr * xr;
  float y = fmaf(cp0, xr, cp1);
  y = fmaf(y, xr, cp2);
  y = fmaf(y, xr, cp3);
  y = fmaf(y, xr, cp4);
  y = fmaf(y, xr, cp5);
  y = fmaf(y, z, xr);
  y = y + 1.0f;
  int n = (int)fx;
  float two_n = __int_as_float((n + 127) << 23);
  float r = y * two_n;
  return fmaxf(r, xc);
}

__device__ __forceinline__ float ref_sigmoid(float x) {
  return 1.0f / (1.0f + xla_expf(-x));
}

// Fast monotone sigmoid for FILTERING only. IDENTICAL expression in k_passA
// and k_wlemit (bit-consistent bins).
__device__ __forceinline__ float fast_sigmoid(float x) {
  float e = __expf(-x);
  return __fdividef(1.0f, 1.0f + e);
}

__device__ __forceinline__ int score_bin(float s) {
  int b = (int)((s - 0.25f) * BIN_SCALE);
  return min(max(b, 0), NBINS - 1);
}

// ---------------- geometry helpers ----------------
__device__ __forceinline__ const float* locate(int img, int box,
    const float* __restrict__ p0, const float* __restrict__ p1, const float* __restrict__ p2,
    int& lvl, int& gx, int& gy, int& anc, float& stride) {
  const float* base; int r, W;
  if (box < NB0)            { lvl = 0; r = box;             W = 80; base = p0 + (size_t)img * NB0 * NCH; stride = 8.0f;  }
  else if (box < NB0 + NB1) { lvl = 1; r = box - NB0;       W = 40; base = p1 + (size_t)img * NB1 * NCH; stride = 16.0f; }
  else                      { lvl = 2; r = box - NB0 - NB1; W = 20; base = p2 + (size_t)img * NB2 * NCH; stride = 32.0f; }
  anc = r % 3;
  int cell = r / 3;
  gx = cell % W;
  gy = cell / W;
  return base + (size_t)r * NCH;
}

__device__ __forceinline__ float clip640(float v) {
  return fminf(fmaxf(v, 0.0f), IMGSZ);
}

__device__ __forceinline__ const float* row_ptr(int img, int box,
    const float* __restrict__ p0, const float* __restrict__ p1, const float* __restrict__ p2) {
  const float* base; int r;
  if (box < NB0)            { base = p0 + (size_t)img * NB0 * NCH; r = box; }
  else if (box < NB0 + NB1) { base = p1 + (size_t)img * NB1 * NCH; r = box - NB0; }
  else                      { base = p2 + (size_t)img * NB2 * NCH; r = box - NB0 - NB1; }
  return base + (size_t)r * NCH;
}

// ---------------- pass A: single-round batched loads, lump-binned histogram ----------
// Round-13 post-mortem: 94us with HBM 13% / VALU 32% / occ 66% -> latency from
// the 2-round dependent chain (obj gate guarded the class loads) + ~11M LDS
// hist atomics (99% in low bins far below tb~3000). Fix: unconditional
// dwordx4-batched loads (one memory round), predicate the compute, and lump
// all bins < LOWBIN into hist[0] via one ballot-aggregated atomic per wave.
__global__ __launch_bounds__(256) void k_passA(const float* __restrict__ p0,
    const float* __restrict__ p1, const float* __restrict__ p2,
    unsigned int* __restrict__ ghist, unsigned short* __restrict__ maxbin) {
  __shared__ unsigned int hist[NBINS];              // 16 KB
  const int tid = threadIdx.x;
  const int img  = blockIdx.x / TILES;
  const int tile = blockIdx.x % TILES;
  const int tbase = tile * TILE;
  const int nbox_tile = min(TILE, NBOX - tbase);
  const int lane = tid & 63;

  for (int i = tid; i < NBINS; i += 256) hist[i] = 0u;
  __syncthreads();

  const int b_local = tid >> 3, part = tid & 7;
  #pragma unroll
  for (int step = 0; step < TILE / 32; ++step) {
    int bl = step * 32 + b_local;
    bool valid = (bl < nbox_tile);
    int box = tbase + min(bl, nbox_tile - 1);     // clamped; invalid blocked below
    const float* row = row_ptr(img, box, p0, p1, p2);

    // ---- issue ALL loads up front (one memory round) ----
    float xo = row[4];                            // broadcast within 8-group
    const float* cls = row + 5 + 10 * part;       // contiguous 10-class segment
    float4a va = *(const float4a*)(cls);
    float4a vb = *(const float4a*)(cls + 4);
    float2a vc = *(const float2a*)(cls + 8);
    float v[10] = { va.x, va.y, va.z, va.w, vb.x, vb.y, vb.z, vb.w, vc.x, vc.y };

    // ---- compute under predicates (ballots below need convergence) ----
    float obj = fast_sigmoid(xo);
    float tcons = 3.0e38f;
    if (valid && obj > 0.2499f) {
      float rr = 0.2499f / obj;
      tcons = __logf(__fdividef(rr, 1.0f - rr)) - 0.05f;
    }

    int mb = 0;
    #pragma unroll
    for (int k = 0; k < 10; ++k) {
      int bin = -1;
      float x = v[k];
      if (x > tcons) {
        float s = obj * fast_sigmoid(x);
        if (s > 0.2499f) bin = score_bin(s);
      }
      if (bin >= LOWBIN) atomicAdd(&hist[bin], 1u);
      unsigned long long bl2 = __ballot(bin >= 0 && bin < LOWBIN);
      if (bl2 != 0ull && lane == (__ffsll(bl2) - 1))
        atomicAdd(&hist[0], (unsigned int)__popcll(bl2));   // lump
      mb = max(mb, bin + 1);                      // fine bin always
    }
    mb = max(mb, __shfl_xor(mb, 1, 8));
    mb = max(mb, __shfl_xor(mb, 2, 8));
    mb = max(mb, __shfl_xor(mb, 4, 8));
    if (valid && part == 0)
      maxbin[(size_t)img * NBOX + tbase + bl] = (unsigned short)mb;
  }
  __syncthreads();

  for (int i = tid; i < NBINS; i += 256) {
    unsigned int v2 = hist[i];
    if (v2) atomicAdd(&ghist[img * NBINS + i], v2);
  }
}

// ---------------- per-image threshold bin with 2-bin safety slack ----------------
__global__ __launch_bounds__(256) void k_thresh(const unsigned int* __restrict__ ghist,
                                                int* __restrict__ tbin) {
  __shared__ unsigned int h[NBINS];
  __shared__ unsigned int psum[256];
  const int tid = threadIdx.x;
  const int img = blockIdx.x;

  for (int i = tid; i < NBINS; i += 256) h[i] = ghist[img * NBINS + i];
  __syncthreads();
  unsigned int ps = 0;
  for (int k = 0; k < 16; ++k) ps += h[tid * 16 + k];
  psum[tid] = ps;
  __syncthreads();
  if (tid == 0) {
    long long cum = 0;
    int tb = 0;
    bool found = false;
    for (int g = 255; g >= 0 && !found; --g) {
      if (cum + (long long)psum[g] >= NTOP) {
        for (int b = g * 16 + 15; b >= g * 16; --b) {
          cum += h[b];
          if (cum >= NTOP) { tb = b; found = true; break; }
        }
      } else {
        cum += psum[g];
      }
    }
    if (!found) tb = 0;
    int tc = (tb >= 2) ? tb - 2 : 0;
    for (int b = tb - 1; b >= tc; --b) cum += h[b];
    while (cum > CAP - 8 && tc < NBINS - 1) { cum -= h[tc]; ++tc; }  // pathological guard
    tbin[img] = tc;
  }
}

// ---------------- fused worklist + emit ----------------
// Block-local compaction of passing rows into LDS, then 8 threads/row with
// contiguous 10-class segments: fast pre-screen (bit-consistent with passA),
// exact XLA-sigmoid gates + values, wave-aggregated slot allocation.
__global__ __launch_bounds__(256) void k_wlemit(const float* __restrict__ p0,
    const float* __restrict__ p1, const float* __restrict__ p2,
    const unsigned short* __restrict__ maxbin, const int* __restrict__ tbin,
    unsigned long long* __restrict__ cand, int* __restrict__ cnt) {
  __shared__ unsigned int list[256];
  __shared__ int lcnt;
  const int tid = threadIdx.x;
  const int lane = tid & 63;
  if (tid == 0) lcnt = 0;
  __syncthreads();

  int idx = blockIdx.x * 256 + tid;
  if (idx < NIMG * NBOX) {
    int img = idx / NBOX;
    int box = idx - img * NBOX;
    if ((int)maxbin[idx] > tbin[img])
      list[atomicAdd(&lcnt, 1)] = ((unsigned int)img << 16) | (unsigned int)box;
  }
  __syncthreads();
  const int n = lcnt;
  const int nsweep = (n + 31) / 32;

  for (int s = 0; s < nsweep; ++s) {
    int r = s * 32 + (tid >> 3);
    int part = tid & 7;
    bool have = (r < n);
    int img = 0, box = 0, nc = 0;
    unsigned int bm = 0;
    float obj_e = -1.0f;
    float v[10];
    if (have) {
      unsigned int e = list[r];
      img = (int)(e >> 16);
      box = (int)(e & 0xFFFFu);
      const float* row = row_ptr(img, box, p0, p1, p2);
      float xo = row[4];
      float obj_f = fast_sigmoid(xo);             // identical expression to passA
      if (obj_f > 0.2499f) {
        const float* cls = row + 5 + 10 * part;
        float4a va = *(const float4a*)(cls);
        float4a vb = *(const float4a*)(cls + 4);
        float2a vc = *(const float2a*)(cls + 8);
        v[0]=va.x; v[1]=va.y; v[2]=va.z; v[3]=va.w;
        v[4]=vb.x; v[5]=vb.y; v[6]=vb.z; v[7]=vb.w;
        v[8]=vc.x; v[9]=vc.y;
        int tc = tbin[img];
        #pragma unroll
        for (int k = 0; k < 10; ++k) {
          float sf = obj_f * fast_sigmoid(v[k]);
          if (sf > 0.2499f && score_bin(sf) >= tc) {
            if (obj_e < 0.0f) obj_e = ref_sigmoid(xo);      // lazy exact obj
            if (obj_e > 0.25f) {
              float se = obj_e * ref_sigmoid(v[k]);          // exact gates
              if (se > 0.25f) { bm |= 1u << k; ++nc; }
            }
          }
        }
      }
    }

    // wave-aggregated base assignment, grouped by img
    int mybase = 0;
    unsigned long long active = __ballot(nc > 0);
    while (active) {
      int leader = __ffsll(active) - 1;
      int limg = __shfl(img, leader);
      bool mine = (nc > 0) && (img == limg);
      unsigned long long grp = __ballot(mine);
      int incl = mine ? nc : 0;
      #pragma unroll
      for (int d = 1; d < 64; d <<= 1) {
        int t = __shfl_up(incl, d);
        if (lane >= d) incl += t;
      }
      int hi = 63 - __clzll(grp);
      int total = __shfl(incl, hi);
      int base = 0;
      if (lane == leader) base = atomicAdd(&cnt[limg], total);
      base = __shfl(base, leader);
      if (mine) mybase = base + incl - nc;
      active &= ~grp;
    }

    // emit exact keys
    if (nc > 0) {
      int pos = mybase;
      #pragma unroll
      for (int k = 0; k < 10; ++k) {
        if (bm & (1u << k)) {
          float se = obj_e * ref_sigmoid(v[k]);   // exact value (bit-identical)
          if (pos < CAP) {
            unsigned int fi = (unsigned int)(box * NCLS + 10 * part + k);
            unsigned long long key =
                ((unsigned long long)__float_as_uint(se) << 32) |
                (unsigned long long)(0xFFFFFFFFu - fi);
            cand[(size_t)img * CAP + pos] = key;
          }
          ++pos;
        }
      }
    }
  }
}

// ---------------- sort + decode top-1000 into boxes8 (one block per image) ----------------
#define SIDX(i) ((i) + ((i) >> 4))

__global__ __launch_bounds__(256) void k_sort(const float* __restrict__ p0,
    const float* __restrict__ p1, const float* __restrict__ p2,
    const float* __restrict__ anchors, const unsigned long long* __restrict__ cand,
    const int* __restrict__ cnt_arr, float* __restrict__ boxes8) {
  __shared__ unsigned long long keys[CAP + CAP / 16];   // 34.8 KB (swizzled)
  __shared__ int n2_sh, cnt_sh;
  const int tid = threadIdx.x;
  const int img = blockIdx.x;

  if (tid == 0) {
    int c = cnt_arr[img];
    c = max(0, min(c, CAP));
    int n2 = 1024;
    while (n2 < c) n2 <<= 1;
    cnt_sh = c; n2_sh = n2;
  }
  __syncthreads();
  const int cnt = cnt_sh;
  const int n2  = n2_sh;

  const unsigned long long* c = cand + (size_t)img * CAP;
  for (int i = tid; i < n2; i += 256) keys[SIDX(i)] = (i < cnt) ? c[i] : 0ull;
  __syncthreads();

  for (int kk = 2; kk <= n2; kk <<= 1) {
    for (int j = kk >> 1; j > 0; j >>= 1) {
      for (int i = tid; i < n2; i += 256) {
        int l = i ^ j;
        if (l > i) {
          unsigned long long a = keys[SIDX(i)], b = keys[SIDX(l)];
          bool up = ((i & kk) == 0);
          bool sw = up ? (a < b) : (a > b);
          if (sw) { keys[SIDX(i)] = b; keys[SIDX(l)] = a; }
        }
      }
      __syncthreads();
    }
  }

  // decode top-1000 -> boxes8[img][1000][8] = {b0,b1,b2,b3,val,label,0,0}
  float* dst = boxes8 + (size_t)img * NTOP * 8;
  for (int i = tid; i < NTOP; i += 256) {
    unsigned long long key = keys[SIDX(i)];
    unsigned int v = (unsigned int)(key >> 32);
    float4 fa, fb;
    if (v) {
      unsigned int idx = 0xFFFFFFFFu - (unsigned int)(key & 0xFFFFFFFFu);
      int box = (int)(idx / NCLS);
      int l   = (int)(idx % NCLS);
      int lvl, gx, gy, anc; float stride;
      const float* ptr = locate(img, box, p0, p1, p2, lvl, gx, gy, anc, stride);
      float sx = ref_sigmoid(ptr[0]);
      float sy = ref_sigmoid(ptr[1]);
      float sw = ref_sigmoid(ptr[2]);
      float sh = ref_sigmoid(ptr[3]);
      float aw = anchors[(lvl * 3 + anc) * 2 + 0];
      float ah = anchors[(lvl * 3 + anc) * 2 + 1];
      float cx = (2.0f * sx - 0.5f + (float)gx) * stride;
      float cy = (2.0f * sy - 0.5f + (float)gy) * stride;
      float ww = (4.0f * (sw * sw)) * aw;
      float hh = (4.0f * (sh * sh)) * ah;
      fa.x = clip640(cx - ww * 0.5f);
      fa.y = clip640(cy - hh * 0.5f);
      fa.z = clip640(cx + ww * 0.5f);
      fa.w = clip640(cy + hh * 0.5f);
      fb.x = __uint_as_float(v);
      fb.y = (float)l;
      fb.z = 0.0f; fb.w = 0.0f;
    } else {
      fa.x = fa.y = fa.z = fa.w = 0.0f;
      fb.x = 0.0f; fb.y = -1.0f; fb.z = 0.0f; fb.w = 0.0f;
    }
    *(float4*)(dst + i * 8)     = fa;
    *(float4*)(dst + i * 8 + 4) = fb;
  }
}

// ---------------- IoU suppression matrix: bit[r][t] = iou(obx[r],obx[t]) > 0.45 ----------
__global__ __launch_bounds__(256) void k_iou(const float* __restrict__ boxes8,
                                             unsigned int* __restrict__ mat) {
  __shared__ float obx[NTOP * 5];   // stride 5 -> lane col-reads are 2-way (free)
  const int img = blockIdx.x / (NTOP / IOU_RPB);
  const int rg  = blockIdx.x % (NTOP / IOU_RPB);
  const float* src = boxes8 + (size_t)img * NTOP * 8;

  for (int t = threadIdx.x; t < NTOP; t += 256) {
    float4 fa = *(const float4*)(src + t * 8);
    float lab = src[t * 8 + 5];
    float off = lab * 4096.0f;          // exact fp32 (ref: lab*MAX_SIZE)
    obx[t * 5 + 0] = fa.x + off;
    obx[t * 5 + 1] = fa.y + off;
    obx[t * 5 + 2] = fa.z + off;
    obx[t * 5 + 3] = fa.w + off;
  }
  __syncthreads();

  const int wave = threadIdx.x >> 6;
  const int lane = threadIdx.x & 63;
  for (int task = wave; task < IOU_RPB * 16; task += 4) {
    int r = rg * IOU_RPB + (task >> 4);
    int w = task & 15;
    float a0 = obx[r * 5 + 0], a1 = obx[r * 5 + 1];   // broadcast reads
    float a2 = obx[r * 5 + 2], a3 = obx[r * 5 + 3];
    float areaA = (a2 - a0) * (a3 - a1);
    int col = w * 64 + lane;
    bool bit = false;
    if (col < NTOP) {
      float o0 = obx[col * 5 + 0], o1 = obx[col * 5 + 1];
      float o2 = obx[col * 5 + 2], o3 = obx[col * 5 + 3];
      float ltx = fmaxf(a0, o0);
      float lty = fmaxf(a1, o1);
      float rbx = fminf(a2, o2);
      float rby = fminf(a3, o3);
      float wx = fmaxf(rbx - ltx, 0.0f);
      float wy = fmaxf(rby - lty, 0.0f);
      float inter = wx * wy;
      float a2r = (o2 - o0) * (o3 - o1);
      float denom = areaA + a2r - inter + 1e-7f;      // ((a1+a2)-inter)+1e-7, contract off
      bit = (inter / denom) > 0.45f;
    }
    unsigned long long m = __ballot(bit);
    if (lane == 0)
      *(unsigned long long*)(mat + ((size_t)img * NTOP + r) * 32 + w * 2) = m;
  }
}

// ---------------- NMS greedy: O(1) serial work per pick ----------
__global__ __launch_bounds__(64) void k_nms(const unsigned int* __restrict__ mat,
    const float* __restrict__ boxes8, const float* __restrict__ scalef,
    float* __restrict__ out) {
  __shared__ uint4 mat_lds4[NTOP * 8];   // 1000 rows x 32 u32 = 128000 B
  unsigned int* mat_lds = (unsigned int*)mat_lds4;
  const int lane = threadIdx.x;
  const int img = blockIdx.x;
  const float* src = boxes8 + (size_t)img * NTOP * 8;

  const uint4* msrc = (const uint4*)(mat + (size_t)img * NTOP * 32);
  for (int i = lane; i < NTOP * 8; i += 64) mat_lds4[i] = msrc[i];

  // alive init: lane l (<32) owns u32 word for bits t in [32l, 32l+32)
  unsigned int aw = 0u;
  for (int w = 0; w < 16; ++w) {
    int t = w * 64 + lane;
    float va = (t < NTOP) ? src[t * 8 + 4] : 0.0f;
    unsigned long long b = __ballot(va > 0.0f);
    if (lane == 2 * w)     aw = (unsigned int)b;
    if (lane == 2 * w + 1) aw = (unsigned int)(b >> 32);
  }
  if (lane >= 32) aw = 0u;
  __syncthreads();

  int pj0 = -1, pj1 = -1;
  for (int i = 0; i < NDET; ++i) {
    unsigned long long bal = __ballot(aw != 0u);
    int j = -1;
    if (bal != 0ull) {
      int L = __ffsll(bal) - 1;
      unsigned int wL = (unsigned int)__shfl((int)aw, L);
      j = L * 32 + (__ffs(wL) - 1);
    }
    if (lane == (i & 63)) { if (i < 64) pj0 = j; else pj1 = j; }
    if (j >= 0 && lane < 32) aw &= ~mat_lds[j * 32 + lane];   // conflict-free
  }

  // parallel emit
  const float scf = scalef[img];
  #pragma unroll
  for (int rep = 0; rep < 2; ++rep) {
    int i = rep * 64 + lane;
    if (i >= NDET) break;
    int j = (rep == 0) ? pj0 : pj1;
    float* orow = out + ((size_t)img * NDET + i) * 6;
    if (j < 0) {
      orow[0] = 0.0f; orow[1] = 0.0f; orow[2] = 0.0f;
      orow[3] = 0.0f; orow[4] = 0.0f; orow[5] = -1.0f;
    } else {
      float4 fa = *(const float4*)(src + j * 8);
      float va = src[j * 8 + 4];
      float lb = src[j * 8 + 5];
      orow[0] = fa.x / scf; orow[1] = fa.y / scf;
      orow[2] = fa.z / scf; orow[3] = fa.w / scf;
      orow[4] = va;
      orow[5] = lb;
    }
  }
}

// ---------------- launcher ----------------
extern "C" void kernel_launch(void* const* d_in, const int* in_sizes, int n_in,
                              void* d_out, int out_size, void* d_ws, size_t ws_size,
                              hipStream_t stream) {
  const float* p0 = (const float*)d_in[0];
  const float* p1 = (const float*)d_in[1];
  const float* p2 = (const float*)d_in[2];
  const float* anchors = (const float*)d_in[3];
  const float* scalef  = (const float*)d_in[4];
  float* out = (float*)d_out;

  char* w = (char*)d_ws;
  // layout (bytes): ghist 262144 | cnt 64 | tbin 64 | pad 64 | cand 524288 |
  //   maxbin 806400 | boxes8 512000 | mat 2048000
  unsigned int* ghist = (unsigned int*)(w);
  int* cnt  = (int*)(w + 262144);
  int* tbin = (int*)(w + 262208);
  unsigned long long* cand = (unsigned long long*)(w + 262336);
  unsigned short* maxbin = (unsigned short*)(w + 262336 + 524288);       // 786624
  float* boxes8 = (float*)(w + 786624 + 806400 + 64);                    // 1593088 (16B aligned)
  unsigned int* mat = (unsigned int*)(w + 1593088 + 512000);             // 2105088

  hipMemsetAsync(ghist, 0, 262144 + 192, stream);   // hist + cnt + tbin

  k_passA<<<dim3(NIMG * TILES), dim3(256), 0, stream>>>(p0, p1, p2, ghist, maxbin);
  k_thresh<<<dim3(NIMG), dim3(256), 0, stream>>>(ghist, tbin);
  k_wlemit<<<dim3((NIMG * NBOX + 255) / 256), dim3(256), 0, stream>>>(p0, p1, p2, maxbin, tbin, cand, cnt);
  k_sort<<<dim3(NIMG), dim3(256), 0, stream>>>(p0, p1, p2, anchors, cand, cnt, boxes8);
  k_iou<<<dim3(NIMG * (NTOP / IOU_RPB)), dim3(256), 0, stream>>>(boxes8, mat);
  k_nms<<<dim3(NIMG), dim3(64), 0, stream>>>(mat, boxes8, scalef, out);
}

// Round 15
// 177.282 us; speedup vs baseline: 1.6874x; 1.2650x over previous
//
#include <hip/hip_runtime.h>
#include <cstdint>
#include <cstddef>

#pragma clang fp contract(off)

constexpr int NIMG  = 16;
constexpr int NB0   = 19200;   // 80*80*3
constexpr int NB1   = 4800;    // 40*40*3
constexpr int NB2   = 1200;    // 20*20*3
constexpr int NBOX  = 25200;
constexpr int NCLS  = 80;
constexpr int NCH   = 85;
constexpr int NBINS = 4096;
constexpr int CAP   = 4096;
constexpr int NTOP  = 1000;
constexpr int NDET  = 100;
constexpr float IMGSZ = 640.0f;
constexpr float BIN_SCALE = 4096.0f / 0.75f;

constexpr int TILE    = 128;
constexpr int TILES   = (NBOX + TILE - 1) / TILE;   // 197

constexpr int IOU_RPB = 40;            // rows per k_iou block (25 blocks/img)
constexpr int LOWBIN  = 546;           // s < 0.35: lump-counted (tb ~ 3000 >> 548)

// 4-byte-aligned vector types: gfx9 global_load_dwordx4 needs only dword align
typedef float float4a __attribute__((ext_vector_type(4), aligned(4)));
typedef float float2a __attribute__((ext_vector_type(2), aligned(4)));

// ---------------- XLA-CPU-matching transcendentals (verified absmax=0) ----------------
__device__ __forceinline__ float xla_expf(float x) {
  const float kLog2e = 1.44269504088896341f;
  const float kC1 = 0.693359375f;
  const float kC2 = -2.12194440e-4f;
  const float cp0 = 1.9875691500e-4f;
  const float cp1 = 1.3981999507e-3f;
  const float cp2 = 8.3334519073e-3f;
  const float cp3 = 4.1665795894e-2f;
  const float cp4 = 1.6666665459e-1f;
  const float cp5 = 5.0000001201e-1f;
  float xc = fminf(x, 88.3762626647950f);
  xc = fmaxf(xc, -88.3762626647949f);
  float fx = floorf(fmaf(xc, kLog2e, 0.5f));
  float xr = fmaf(fx, -kC1, xc);
  xr = fmaf(fx, -kC2, xr);
  float z = xr * xr;
  float y = fmaf(cp0, xr, cp1);
  y = fmaf(y, xr, cp2);
  y = fmaf(y, xr, cp3);
  y = fmaf(y, xr, cp4);
  y = fmaf(y, xr, cp5);
  y = fmaf(y, z, xr);
  y = y + 1.0f;
  int n = (int)fx;
  float two_n = __int_as_float((n + 127) << 23);
  float r = y * two_n;
  return fmaxf(r, xc);
}

__device__ __forceinline__ float ref_sigmoid(float x) {
  return 1.0f / (1.0f + xla_expf(-x));
}

// Fast monotone sigmoid for FILTERING only. IDENTICAL expression in k_passA
// and k_wlemit (bit-consistent bins).
__device__ __forceinline__ float fast_sigmoid(float x) {
  float e = __expf(-x);
  return __fdividef(1.0f, 1.0f + e);
}

__device__ __forceinline__ int score_bin(float s) {
  int b = (int)((s - 0.25f) * BIN_SCALE);
  return min(max(b, 0), NBINS - 1);
}

// ---------------- geometry helpers ----------------
__device__ __forceinline__ const float* locate(int img, int box,
    const float* __restrict__ p0, const float* __restrict__ p1, const float* __restrict__ p2,
    int& lvl, int& gx, int& gy, int& anc, float& stride) {
  const float* base; int r, W;
  if (box < NB0)            { lvl = 0; r = box;             W = 80; base = p0 + (size_t)img * NB0 * NCH; stride = 8.0f;  }
  else if (box < NB0 + NB1) { lvl = 1; r = box - NB0;       W = 40; base = p1 + (size_t)img * NB1 * NCH; stride = 16.0f; }
  else                      { lvl = 2; r = box - NB0 - NB1; W = 20; base = p2 + (size_t)img * NB2 * NCH; stride = 32.0f; }
  anc = r % 3;
  int cell = r / 3;
  gx = cell % W;
  gy = cell / W;
  return base + (size_t)r * NCH;
}

__device__ __forceinline__ float clip640(float v) {
  return fminf(fmaxf(v, 0.0f), IMGSZ);
}

__device__ __forceinline__ const float* row_ptr(int img, int box,
    const float* __restrict__ p0, const float* __restrict__ p1, const float* __restrict__ p2) {
  const float* base; int r;
  if (box < NB0)            { base = p0 + (size_t)img * NB0 * NCH; r = box; }
  else if (box < NB0 + NB1) { base = p1 + (size_t)img * NB1 * NCH; r = box - NB0; }
  else                      { base = p2 + (size_t)img * NB2 * NCH; r = box - NB0 - NB1; }
  return base + (size_t)r * NCH;
}

// ---------------- pass A: single-round batched loads, register-lumped histogram ----------
// Round-14 post-mortem: VALU 48% — the per-class-slot ballot aggregation
// (10 ballots+popc per step) was the instruction hog. Lump counts now
// accumulate in a register and reduce once per wave at block end (identical
// sum -> bit-identical histogram -> identical downstream).
__global__ __launch_bounds__(256) void k_passA(const float* __restrict__ p0,
    const float* __restrict__ p1, const float* __restrict__ p2,
    unsigned int* __restrict__ ghist, unsigned short* __restrict__ maxbin) {
  __shared__ unsigned int hist[NBINS];              // 16 KB
  const int tid = threadIdx.x;
  const int img  = blockIdx.x / TILES;
  const int tile = blockIdx.x % TILES;
  const int tbase = tile * TILE;
  const int nbox_tile = min(TILE, NBOX - tbase);
  const int lane = tid & 63;

  for (int i = tid; i < NBINS; i += 256) hist[i] = 0u;
  __syncthreads();

  const int b_local = tid >> 3, part = tid & 7;
  int lowc = 0;                                    // register lump accumulator
  #pragma unroll
  for (int step = 0; step < TILE / 32; ++step) {
    int bl = step * 32 + b_local;
    bool valid = (bl < nbox_tile);
    int box = tbase + min(bl, nbox_tile - 1);     // clamped; invalid blocked below
    const float* row = row_ptr(img, box, p0, p1, p2);

    // ---- issue ALL loads up front (one memory round) ----
    float xo = row[4];
    const float* cls = row + 5 + 10 * part;       // contiguous 10-class segment
    float4a va = *(const float4a*)(cls);
    float4a vb = *(const float4a*)(cls + 4);
    float2a vc = *(const float2a*)(cls + 8);
    float v[10] = { va.x, va.y, va.z, va.w, vb.x, vb.y, vb.z, vb.w, vc.x, vc.y };

    // ---- compute under predicates ----
    float obj = fast_sigmoid(xo);
    float tcons = 3.0e38f;
    if (valid && obj > 0.2499f) {
      float rr = 0.2499f / obj;
      tcons = __logf(__fdividef(rr, 1.0f - rr)) - 0.05f;
    }

    int mb = 0;
    #pragma unroll
    for (int k = 0; k < 10; ++k) {
      int bin = -1;
      float x = v[k];
      if (x > tcons) {
        float s = obj * fast_sigmoid(x);
        if (s > 0.2499f) bin = score_bin(s);
      }
      if (bin >= LOWBIN) atomicAdd(&hist[bin], 1u);       // rare (~1k/image)
      lowc += (bin >= 0 && bin < LOWBIN) ? 1 : 0;         // register lump
      mb = max(mb, bin + 1);
    }
    mb = max(mb, __shfl_xor(mb, 1, 8));
    mb = max(mb, __shfl_xor(mb, 2, 8));
    mb = max(mb, __shfl_xor(mb, 4, 8));
    if (valid && part == 0)
      maxbin[(size_t)img * NBOX + tbase + bl] = (unsigned short)mb;
  }

  // one wave-reduce + one atomic per wave for the lump bucket
  #pragma unroll
  for (int d = 1; d < 64; d <<= 1) lowc += __shfl_xor(lowc, d);
  if (lane == 0 && lowc) atomicAdd(&hist[0], (unsigned int)lowc);
  __syncthreads();

  for (int i = tid; i < NBINS; i += 256) {
    unsigned int v2 = hist[i];
    if (v2) atomicAdd(&ghist[img * NBINS + i], v2);
  }
}

// ---------------- per-image threshold bin with 2-bin safety slack ----------------
__global__ __launch_bounds__(256) void k_thresh(const unsigned int* __restrict__ ghist,
                                                int* __restrict__ tbin) {
  __shared__ unsigned int h[NBINS];
  __shared__ unsigned int psum[256];
  const int tid = threadIdx.x;
  const int img = blockIdx.x;

  for (int i = tid; i < NBINS; i += 256) h[i] = ghist[img * NBINS + i];
  __syncthreads();
  unsigned int ps = 0;
  for (int k = 0; k < 16; ++k) ps += h[tid * 16 + k];
  psum[tid] = ps;
  __syncthreads();
  if (tid == 0) {
    long long cum = 0;
    int tb = 0;
    bool found = false;
    for (int g = 255; g >= 0 && !found; --g) {
      if (cum + (long long)psum[g] >= NTOP) {
        for (int b = g * 16 + 15; b >= g * 16; --b) {
          cum += h[b];
          if (cum >= NTOP) { tb = b; found = true; break; }
        }
      } else {
        cum += psum[g];
      }
    }
    if (!found) tb = 0;
    int tc = (tb >= 2) ? tb - 2 : 0;
    for (int b = tb - 1; b >= tc; --b) cum += h[b];
    while (cum > CAP - 8 && tc < NBINS - 1) { cum -= h[tc]; ++tc; }  // pathological guard
    tbin[img] = tc;
  }
}

// ---------------- fused worklist + emit ----------------
__global__ __launch_bounds__(256) void k_wlemit(const float* __restrict__ p0,
    const float* __restrict__ p1, const float* __restrict__ p2,
    const unsigned short* __restrict__ maxbin, const int* __restrict__ tbin,
    unsigned long long* __restrict__ cand, int* __restrict__ cnt) {
  __shared__ unsigned int list[256];
  __shared__ int lcnt;
  const int tid = threadIdx.x;
  const int lane = tid & 63;
  if (tid == 0) lcnt = 0;
  __syncthreads();

  int idx = blockIdx.x * 256 + tid;
  if (idx < NIMG * NBOX) {
    int img = idx / NBOX;
    int box = idx - img * NBOX;
    if ((int)maxbin[idx] > tbin[img])
      list[atomicAdd(&lcnt, 1)] = ((unsigned int)img << 16) | (unsigned int)box;
  }
  __syncthreads();
  const int n = lcnt;
  const int nsweep = (n + 31) / 32;

  for (int s = 0; s < nsweep; ++s) {
    int r = s * 32 + (tid >> 3);
    int part = tid & 7;
    bool have = (r < n);
    int img = 0, box = 0, nc = 0;
    unsigned int bm = 0;
    float obj_e = -1.0f;
    float v[10];
    if (have) {
      unsigned int e = list[r];
      img = (int)(e >> 16);
      box = (int)(e & 0xFFFFu);
      const float* row = row_ptr(img, box, p0, p1, p2);
      float xo = row[4];
      float obj_f = fast_sigmoid(xo);             // identical expression to passA
      if (obj_f > 0.2499f) {
        const float* cls = row + 5 + 10 * part;
        float4a va = *(const float4a*)(cls);
        float4a vb = *(const float4a*)(cls + 4);
        float2a vc = *(const float2a*)(cls + 8);
        v[0]=va.x; v[1]=va.y; v[2]=va.z; v[3]=va.w;
        v[4]=vb.x; v[5]=vb.y; v[6]=vb.z; v[7]=vb.w;
        v[8]=vc.x; v[9]=vc.y;
        int tc = tbin[img];
        #pragma unroll
        for (int k = 0; k < 10; ++k) {
          float sf = obj_f * fast_sigmoid(v[k]);
          if (sf > 0.2499f && score_bin(sf) >= tc) {
            if (obj_e < 0.0f) obj_e = ref_sigmoid(xo);      // lazy exact obj
            if (obj_e > 0.25f) {
              float se = obj_e * ref_sigmoid(v[k]);          // exact gates
              if (se > 0.25f) { bm |= 1u << k; ++nc; }
            }
          }
        }
      }
    }

    // wave-aggregated base assignment, grouped by img
    int mybase = 0;
    unsigned long long active = __ballot(nc > 0);
    while (active) {
      int leader = __ffsll(active) - 1;
      int limg = __shfl(img, leader);
      bool mine = (nc > 0) && (img == limg);
      unsigned long long grp = __ballot(mine);
      int incl = mine ? nc : 0;
      #pragma unroll
      for (int d = 1; d < 64; d <<= 1) {
        int t = __shfl_up(incl, d);
        if (lane >= d) incl += t;
      }
      int hi = 63 - __clzll(grp);
      int total = __shfl(incl, hi);
      int base = 0;
      if (lane == leader) base = atomicAdd(&cnt[limg], total);
      base = __shfl(base, leader);
      if (mine) mybase = base + incl - nc;
      active &= ~grp;
    }

    // emit exact keys
    if (nc > 0) {
      int pos = mybase;
      #pragma unroll
      for (int k = 0; k < 10; ++k) {
        if (bm & (1u << k)) {
          float se = obj_e * ref_sigmoid(v[k]);   // exact value (bit-identical)
          if (pos < CAP) {
            unsigned int fi = (unsigned int)(box * NCLS + 10 * part + k);
            unsigned long long key =
                ((unsigned long long)__float_as_uint(se) << 32) |
                (unsigned long long)(0xFFFFFFFFu - fi);
            cand[(size_t)img * CAP + pos] = key;
          }
          ++pos;
        }
      }
    }
  }
}

// ---------------- sort + decode top-1000 into boxes8 (1024 threads/img) ----------------
// Round-14: 256 threads made each bitonic phase 16 strided iterations; 1024
// threads cut that to 4 (same swizzled LDS layout, same key order).
#define SIDX(i) ((i) + ((i) >> 4))

__global__ __launch_bounds__(1024) void k_sort(const float* __restrict__ p0,
    const float* __restrict__ p1, const float* __restrict__ p2,
    const float* __restrict__ anchors, const unsigned long long* __restrict__ cand,
    const int* __restrict__ cnt_arr, float* __restrict__ boxes8) {
  __shared__ unsigned long long keys[CAP + CAP / 16];   // 34.8 KB (swizzled)
  __shared__ int n2_sh, cnt_sh;
  const int tid = threadIdx.x;
  const int img = blockIdx.x;

  if (tid == 0) {
    int c = cnt_arr[img];
    c = max(0, min(c, CAP));
    int n2 = 1024;
    while (n2 < c) n2 <<= 1;
    cnt_sh = c; n2_sh = n2;
  }
  __syncthreads();
  const int cnt = cnt_sh;
  const int n2  = n2_sh;

  const unsigned long long* c = cand + (size_t)img * CAP;
  for (int i = tid; i < n2; i += 1024) keys[SIDX(i)] = (i < cnt) ? c[i] : 0ull;
  __syncthreads();

  for (int kk = 2; kk <= n2; kk <<= 1) {
    for (int j = kk >> 1; j > 0; j >>= 1) {
      for (int i = tid; i < n2; i += 1024) {
        int l = i ^ j;
        if (l > i) {
          unsigned long long a = keys[SIDX(i)], b = keys[SIDX(l)];
          bool up = ((i & kk) == 0);
          bool sw = up ? (a < b) : (a > b);
          if (sw) { keys[SIDX(i)] = b; keys[SIDX(l)] = a; }
        }
      }
      __syncthreads();
    }
  }

  // decode top-1000 -> boxes8[img][1000][8] = {b0,b1,b2,b3,val,label,0,0}
  float* dst = boxes8 + (size_t)img * NTOP * 8;
  if (tid < NTOP) {
    int i = tid;
    unsigned long long key = keys[SIDX(i)];
    unsigned int v = (unsigned int)(key >> 32);
    float4 fa, fb;
    if (v) {
      unsigned int idx = 0xFFFFFFFFu - (unsigned int)(key & 0xFFFFFFFFu);
      int box = (int)(idx / NCLS);
      int l   = (int)(idx % NCLS);
      int lvl, gx, gy, anc; float stride;
      const float* ptr = locate(img, box, p0, p1, p2, lvl, gx, gy, anc, stride);
      float sx = ref_sigmoid(ptr[0]);
      float sy = ref_sigmoid(ptr[1]);
      float sw = ref_sigmoid(ptr[2]);
      float sh = ref_sigmoid(ptr[3]);
      float aw = anchors[(lvl * 3 + anc) * 2 + 0];
      float ah = anchors[(lvl * 3 + anc) * 2 + 1];
      float cx = (2.0f * sx - 0.5f + (float)gx) * stride;
      float cy = (2.0f * sy - 0.5f + (float)gy) * stride;
      float ww = (4.0f * (sw * sw)) * aw;
      float hh = (4.0f * (sh * sh)) * ah;
      fa.x = clip640(cx - ww * 0.5f);
      fa.y = clip640(cy - hh * 0.5f);
      fa.z = clip640(cx + ww * 0.5f);
      fa.w = clip640(cy + hh * 0.5f);
      fb.x = __uint_as_float(v);
      fb.y = (float)l;
      fb.z = 0.0f; fb.w = 0.0f;
    } else {
      fa.x = fa.y = fa.z = fa.w = 0.0f;
      fb.x = 0.0f; fb.y = -1.0f; fb.z = 0.0f; fb.w = 0.0f;
    }
    *(float4*)(dst + i * 8)     = fa;
    *(float4*)(dst + i * 8 + 4) = fb;
  }
}

// ---------------- IoU suppression matrix: bit[r][t] = iou(obx[r],obx[t]) > 0.45 ----------
__global__ __launch_bounds__(256) void k_iou(const float* __restrict__ boxes8,
                                             unsigned int* __restrict__ mat) {
  __shared__ float obx[NTOP * 5];   // stride 5 -> lane col-reads are 2-way (free)
  const int img = blockIdx.x / (NTOP / IOU_RPB);
  const int rg  = blockIdx.x % (NTOP / IOU_RPB);
  const float* src = boxes8 + (size_t)img * NTOP * 8;

  for (int t = threadIdx.x; t < NTOP; t += 256) {
    float4 fa = *(const float4*)(src + t * 8);
    float lab = src[t * 8 + 5];
    float off = lab * 4096.0f;          // exact fp32 (ref: lab*MAX_SIZE)
    obx[t * 5 + 0] = fa.x + off;
    obx[t * 5 + 1] = fa.y + off;
    obx[t * 5 + 2] = fa.z + off;
    obx[t * 5 + 3] = fa.w + off;
  }
  __syncthreads();

  const int wave = threadIdx.x >> 6;
  const int lane = threadIdx.x & 63;
  for (int task = wave; task < IOU_RPB * 16; task += 4) {
    int r = rg * IOU_RPB + (task >> 4);
    int w = task & 15;
    float a0 = obx[r * 5 + 0], a1 = obx[r * 5 + 1];   // broadcast reads
    float a2 = obx[r * 5 + 2], a3 = obx[r * 5 + 3];
    float areaA = (a2 - a0) * (a3 - a1);
    int col = w * 64 + lane;
    bool bit = false;
    if (col < NTOP) {
      float o0 = obx[col * 5 + 0], o1 = obx[col * 5 + 1];
      float o2 = obx[col * 5 + 2], o3 = obx[col * 5 + 3];
      float ltx = fmaxf(a0, o0);
      float lty = fmaxf(a1, o1);
      float rbx = fminf(a2, o2);
      float rby = fminf(a3, o3);
      float wx = fmaxf(rbx - ltx, 0.0f);
      float wy = fmaxf(rby - lty, 0.0f);
      float inter = wx * wy;
      float a2r = (o2 - o0) * (o3 - o1);
      float denom = areaA + a2r - inter + 1e-7f;      // ((a1+a2)-inter)+1e-7, contract off
      bit = (inter / denom) > 0.45f;
    }
    unsigned long long m = __ballot(bit);
    if (lane == 0)
      *(unsigned long long*)(mat + ((size_t)img * NTOP + r) * 32 + w * 2) = m;
  }
}

// ---------------- NMS greedy: 256-thread staging, wave-0 greedy ----------
__global__ __launch_bounds__(256) void k_nms(const unsigned int* __restrict__ mat,
    const float* __restrict__ boxes8, const float* __restrict__ scalef,
    float* __restrict__ out) {
  __shared__ uint4 mat_lds4[NTOP * 8];   // 1000 rows x 32 u32 = 128000 B
  unsigned int* mat_lds = (unsigned int*)mat_lds4;
  const int tid = threadIdx.x;
  const int lane = tid & 63;
  const int img = blockIdx.x;
  const float* src = boxes8 + (size_t)img * NTOP * 8;

  // 4-wave staging of the 128 KB matrix (round-14: 1 wave = 4x slower)
  const uint4* msrc = (const uint4*)(mat + (size_t)img * NTOP * 32);
  for (int i = tid; i < NTOP * 8; i += 256) mat_lds4[i] = msrc[i];
  __syncthreads();
  if (tid >= 64) return;                 // wave 0 only from here

  // alive init: lane l (<32) owns u32 word for bits t in [32l, 32l+32)
  unsigned int aw = 0u;
  for (int w = 0; w < 16; ++w) {
    int t = w * 64 + lane;
    float va = (t < NTOP) ? src[t * 8 + 4] : 0.0f;
    unsigned long long b = __ballot(va > 0.0f);
    if (lane == 2 * w)     aw = (unsigned int)b;
    if (lane == 2 * w + 1) aw = (unsigned int)(b >> 32);
  }
  if (lane >= 32) aw = 0u;

  int pj0 = -1, pj1 = -1;
  for (int i = 0; i < NDET; ++i) {
    unsigned long long bal = __ballot(aw != 0u);
    int j = -1;
    if (bal != 0ull) {
      int L = __ffsll(bal) - 1;
      unsigned int wL = (unsigned int)__shfl((int)aw, L);
      j = L * 32 + (__ffs(wL) - 1);
    }
    if (lane == (i & 63)) { if (i < 64) pj0 = j; else pj1 = j; }
    if (j >= 0 && lane < 32) aw &= ~mat_lds[j * 32 + lane];   // conflict-free
  }

  // parallel emit
  const float scf = scalef[img];
  #pragma unroll
  for (int rep = 0; rep < 2; ++rep) {
    int i = rep * 64 + lane;
    if (i >= NDET) break;
    int j = (rep == 0) ? pj0 : pj1;
    float* orow = out + ((size_t)img * NDET + i) * 6;
    if (j < 0) {
      orow[0] = 0.0f; orow[1] = 0.0f; orow[2] = 0.0f;
      orow[3] = 0.0f; orow[4] = 0.0f; orow[5] = -1.0f;
    } else {
      float4 fa = *(const float4*)(src + j * 8);
      float va = src[j * 8 + 4];
      float lb = src[j * 8 + 5];
      orow[0] = fa.x / scf; orow[1] = fa.y / scf;
      orow[2] = fa.z / scf; orow[3] = fa.w / scf;
      orow[4] = va;
      orow[5] = lb;
    }
  }
}

// ---------------- launcher ----------------
extern "C" void kernel_launch(void* const* d_in, const int* in_sizes, int n_in,
                              void* d_out, int out_size, void* d_ws, size_t ws_size,
                              hipStream_t stream) {
  const float* p0 = (const float*)d_in[0];
  const float* p1 = (const float*)d_in[1];
  const float* p2 = (const float*)d_in[2];
  const float* anchors = (const float*)d_in[3];
  const float* scalef  = (const float*)d_in[4];
  float* out = (float*)d_out;

  char* w = (char*)d_ws;
  // layout (bytes): ghist 262144 | cnt 64 | tbin 64 | pad 64 | cand 524288 |
  //   maxbin 806400 | boxes8 512000 | mat 2048000
  unsigned int* ghist = (unsigned int*)(w);
  int* cnt  = (int*)(w + 262144);
  int* tbin = (int*)(w + 262208);
  unsigned long long* cand = (unsigned long long*)(w + 262336);
  unsigned short* maxbin = (unsigned short*)(w + 262336 + 524288);       // 786624
  float* boxes8 = (float*)(w + 786624 + 806400 + 64);                    // 1593088 (16B aligned)
  unsigned int* mat = (unsigned int*)(w + 1593088 + 512000);             // 2105088

  hipMemsetAsync(ghist, 0, 262144 + 192, stream);   // hist + cnt + tbin

  k_passA<<<dim3(NIMG * TILES), dim3(256), 0, stream>>>(p0, p1, p2, ghist, maxbin);
  k_thresh<<<dim3(NIMG), dim3(256), 0, stream>>>(ghist, tbin);
  k_wlemit<<<dim3((NIMG * NBOX + 255) / 256), dim3(256), 0, stream>>>(p0, p1, p2, maxbin, tbin, cand, cnt);
  k_sort<<<dim3(NIMG), dim3(1024), 0, stream>>>(p0, p1, p2, anchors, cand, cnt, boxes8);
  k_iou<<<dim3(NIMG * (NTOP / IOU_RPB)), dim3(256), 0, stream>>>(boxes8, mat);
  k_nms<<<dim3(NIMG), dim3(256), 0, stream>>>(mat, boxes8, scalef, out);
}